// Round 9
// baseline (147.099 us; speedup 1.0000x reference)
//
#include <hip/hip_runtime.h>
#include <hip/hip_bf16.h>
#include <stdint.h>

#define BSZ 64
#define NRG 36
#define VD  2048
#define QD  1024
#define CS  512
#define RD  256
#define KP  2080                 // 2052 padded to 32
#define MR  (BSZ*NRG)            // 2304
#define TRI  666                 // upper-triangle pairs (i<=j) per batch
#define TRIP 704                 // padded per-batch rows (11*64)
#define MTRI (BSZ*TRIP)          // 45056

typedef __bf16 bf16x8 __attribute__((ext_vector_type(8)));
typedef float  f32x4  __attribute__((ext_vector_type(4)));

static __device__ __forceinline__ f32x4 mfma16(bf16x8 a, bf16x8 b, f32x4 c) {
    return __builtin_amdgcn_mfma_f32_16x16x32_bf16(a, b, c, 0, 0, 0);
}

// async global->LDS, 16B per lane (dest = wave-uniform base + lane*16)
static __device__ __forceinline__ void load_lds16(const __bf16* g, __bf16* l) {
    __builtin_amdgcn_global_load_lds(
        (const __attribute__((address_space(1))) uint32_t*)(const void*)g,
        (__attribute__((address_space(3))) uint32_t*)(void*)l,
        16, 0, 0);
}

// ---- merged prep: Xc rows, 3 g-major weights, tri LUT ----
__global__ __launch_bounds__(256) void k_prep(
    const float* __restrict__ X, const float* __restrict__ pos,
    const float* __restrict__ Wv, const float* __restrict__ W1,
    const float* __restrict__ W2,
    __bf16* __restrict__ Xc, __bf16* __restrict__ Wvg,
    __bf16* __restrict__ W1g, __bf16* __restrict__ W2g,
    int* __restrict__ lut)
{
    int id = blockIdx.x;
    if (id < MR) {               // ---- Xc row: [X | pos | 0-pad] ----
        const float* xr = X + (size_t)id * VD;
        const float* pr = pos + (size_t)id * 4;
        __bf16* o = Xc + (size_t)id * KP;
        for (int c = threadIdx.x; c < KP; c += 256) {
            float v = 0.f;
            if (c < VD) v = xr[c];
            else if (c < VD + 4) v = pr[c - VD];
            o[c] = (__bf16)v;
        }
        return;
    }
    id -= MR;
    if (id < 520 + 64 + 32) {    // ---- weight tile -> Wg[k/8][N][8] ----
        const float* W; __bf16* Wg; int K, N, nbx;
        if (id < 520)      {          W = Wv; Wg = Wvg; K = VD + 4; N = CS; nbx = CS / 64; }
        else if (id < 584) { id -= 520; W = W1; Wg = W1g; K = CS;     N = RD; nbx = RD / 64; }
        else               { id -= 584; W = W2; Wg = W2g; K = RD;     N = RD; nbx = RD / 64; }
        int bx = id % nbx, by = id / nbx;
        int g = by * 4 + (threadIdx.x >> 6);
        int n = bx * 64 + (threadIdx.x & 63);
        bf16x8 v;
        #pragma unroll
        for (int e = 0; e < 8; ++e) {
            int k = g * 8 + e;
            v[e] = (__bf16)((k < K) ? W[(size_t)k * N + n] : 0.f);
        }
        *(bf16x8*)(Wg + ((size_t)g * N + n) * 8) = v;
        return;
    }
    // ---- lut (size TRIP, clamped past TRI) ----
    for (int t = threadIdx.x; t < TRIP; t += 256) {
        int tt = (t < TRI) ? t : (TRI - 1);
        int i = 0;
        while (tt >= NRG - i) { tt -= NRG - i; ++i; }
        lut[t] = (i << 8) | (i + tt);
    }
}

// ---- Qp[b][c] = relu(Q[b]@Wq[:,c] + bq[c]) fp32, split-K parallel ----
__global__ __launch_bounds__(256) void k_qproj(
    const float* __restrict__ Q, const float* __restrict__ Wq,
    const float* __restrict__ bq, float* __restrict__ Qp) {
    int b   = blockIdx.x;
    int col = blockIdx.y * 64 + (threadIdx.x & 63);
    int ks  = threadIdx.x >> 6;
    const float* q = Q  + (size_t)b * QD + ks * 256;
    const float* w = Wq + (size_t)(ks * 256) * CS + col;
    float acc = 0.f;
    #pragma unroll 8
    for (int k = 0; k < 256; ++k)
        acc = fmaf(q[k], w[(size_t)k * CS], acc);
    __shared__ float red[256];
    red[threadIdx.x] = acc;
    __syncthreads();
    if (ks == 0) {
        float v = red[threadIdx.x] + red[threadIdx.x + 64]
                + red[threadIdx.x + 128] + red[threadIdx.x + 192] + bq[col];
        Qp[(size_t)b * CS + col] = fmaxf(v, 0.f);
    }
}

// ---- pack: Pair[b][t][c] = Xs[b,i,c]*Xs[b,j,c], bf16, memory-bound ----
__global__ __launch_bounds__(256) void k_pack(
    const __bf16* __restrict__ Xs, const int* __restrict__ lut,
    __bf16* __restrict__ Pair)
{
    int b = blockIdx.y;
    int t = blockIdx.x * 8 + (threadIdx.x >> 5);
    int c = (threadIdx.x & 31) * 16;
    int ij = lut[t];
    int i = ij >> 8, j = ij & 255;
    const bf16x8* xi = (const bf16x8*)(Xs + ((size_t)(b * NRG + i)) * CS + c);
    const bf16x8* xj = (const bf16x8*)(Xs + ((size_t)(b * NRG + j)) * CS + c);
    bf16x8 a0 = xi[0], a1 = xi[1], c0 = xj[0], c1 = xj[1];
    bf16x8 p0, p1;
    #pragma unroll
    for (int e = 0; e < 8; ++e) {
        p0[e] = (__bf16)((float)a0[e] * (float)c0[e]);
        p1[e] = (__bf16)((float)a1[e] * (float)c1[e]);
    }
    bf16x8* o = (bf16x8*)(Pair + ((size_t)b * TRIP + t) * CS + c);
    o[0] = p0;
    o[1] = p1;
}

// ---- generic 64x64 MFMA GEMM, ring-4 LDS, counted vmcnt (k_g1 clone) ----
// MODE 1: relu(acc+bias)+Qp[row/NRG] -> bf16   (G1: Xs)
// MODE 3: relu(acc+bias)             -> bf16   (G2: H)
// MODE 2: relu(acc+bias) -> f32, triangular dual-store (G3: out)
template<int MODE>
__global__ __launch_bounds__(256) void k_mm(
    const __bf16* __restrict__ A, int lda,
    const __bf16* __restrict__ Bg, int NB,     // g-major [K/8][NB][8]
    const float* __restrict__ bias,
    const float* __restrict__ Qp,
    void* __restrict__ Out, int ldo, int K,
    const int* __restrict__ lut)
{
    __shared__ __align__(16) __bf16 sA[4][4 * 64 * 8];
    __shared__ __align__(16) __bf16 sB[4][4 * 64 * 8];

    const int tid = threadIdx.x;
    const int lane = tid & 63;
    const int w = tid >> 6;
    const int wm = w & 1, wn = w >> 1;
    const int l15 = lane & 15, l4 = lane >> 4;
    const int m0 = blockIdx.x * 64;
    const int n0 = blockIdx.y * 64;
    const int sg = tid >> 6;
    const int sr = tid & 63;

    auto stage = [&](int kt, int slot) {
        load_lds16(A + (size_t)(m0 + sr) * lda + kt * 32 + sg * 8,
                   &sA[slot][0] + (size_t)tid * 8);
        load_lds16(Bg + ((size_t)(kt * 4 + sg) * NB + n0 + sr) * 8,
                   &sB[slot][0] + (size_t)tid * 8);
    };

    const int NKT = K >> 5;
    stage(0, 0);
    stage(1, 1);

    f32x4 acc[2][2] = {};
    for (int kt = 0; kt < NKT; ++kt) {
        if (kt + 2 < NKT) stage(kt + 2, (kt + 2) & 3);
        if (kt + 2 < NKT)      asm volatile("s_waitcnt vmcnt(4)" ::: "memory");
        else if (kt + 1 < NKT) asm volatile("s_waitcnt vmcnt(2)" ::: "memory");
        else                   asm volatile("s_waitcnt vmcnt(0)" ::: "memory");
        __builtin_amdgcn_s_barrier();

        const __bf16* a_base = &sA[kt & 3][0];
        const __bf16* b_base = &sB[kt & 3][0];
        bf16x8 af[2], bf[2];
        #pragma unroll
        for (int f = 0; f < 2; ++f)
            af[f] = *(const bf16x8*)(a_base + ((size_t)l4 * 64 + wm * 32 + f * 16 + l15) * 8);
        #pragma unroll
        for (int g = 0; g < 2; ++g)
            bf[g] = *(const bf16x8*)(b_base + ((size_t)l4 * 64 + wn * 32 + g * 16 + l15) * 8);
        __builtin_amdgcn_s_setprio(1);
        #pragma unroll
        for (int f = 0; f < 2; ++f)
            #pragma unroll
            for (int g = 0; g < 2; ++g)
                acc[f][g] = mfma16(af[f], bf[g], acc[f][g]);
        __builtin_amdgcn_s_setprio(0);
    }

    if (MODE != 2) {
        #pragma unroll
        for (int f = 0; f < 2; ++f) {
            int row0 = m0 + wm * 32 + f * 16 + l4 * 4;
            #pragma unroll
            for (int g = 0; g < 2; ++g) {
                int col = n0 + wn * 32 + g * 16 + l15;
                float bb = bias[col];
                #pragma unroll
                for (int r = 0; r < 4; ++r) {
                    int row = row0 + r;
                    float v = fmaxf(acc[f][g][r] + bb, 0.f);
                    if (MODE == 1) v += Qp[(size_t)(row / NRG) * CS + col];
                    ((__bf16*)Out)[(size_t)row * ldo + col] = (__bf16)v;
                }
            }
        }
    } else {
        const int b = m0 / TRIP;     // 64-blocks never cross batches (704 = 11*64)
        #pragma unroll
        for (int f = 0; f < 2; ++f) {
            int row0 = m0 + wm * 32 + f * 16 + l4 * 4;
            #pragma unroll
            for (int r = 0; r < 4; ++r) {
                int row = row0 + r;
                int t = row - b * TRIP;
                if (t < TRI) {
                    int ij = lut[t];
                    int i = ij >> 8, j = ij & 255;
                    float* o1 = (float*)Out + ((size_t)((b * NRG + i) * NRG + j)) * RD;
                    float* o2 = (float*)Out + ((size_t)((b * NRG + j) * NRG + i)) * RD;
                    #pragma unroll
                    for (int g = 0; g < 2; ++g) {
                        int col = n0 + wn * 32 + g * 16 + l15;
                        float v = fmaxf(acc[f][g][r] + bias[col], 0.f);
                        o1[col] = v;
                        o2[col] = v;
                    }
                }
            }
        }
    }
}

extern "C" void kernel_launch(void* const* d_in, const int* in_sizes, int n_in,
                              void* d_out, int out_size, void* d_ws, size_t ws_size,
                              hipStream_t stream) {
    const float* X   = (const float*)d_in[0];
    const float* Q   = (const float*)d_in[1];
    const float* pos = (const float*)d_in[2];
    const float* Wv  = (const float*)d_in[3];
    const float* bv  = (const float*)d_in[4];
    const float* Wq  = (const float*)d_in[5];
    const float* bq  = (const float*)d_in[6];
    const float* W1  = (const float*)d_in[7];
    const float* b1  = (const float*)d_in[8];
    const float* W2  = (const float*)d_in[9];
    const float* b2  = (const float*)d_in[10];

    char* ws = (char*)d_ws;
    size_t off = 0;
    auto alloc = [&](size_t bytes) {
        char* p = ws + off;
        off = (off + bytes + 255) & ~(size_t)255;
        return p;
    };
    __bf16* Wvg = (__bf16*)alloc((size_t)(KP/8) * CS * 8 * 2);   // 2.1 MB
    __bf16* W1g = (__bf16*)alloc((size_t)(CS/8) * RD * 8 * 2);   // 256 KB
    __bf16* W2g = (__bf16*)alloc((size_t)(RD/8) * RD * 8 * 2);   // 128 KB
    float*  Qp  = (float*) alloc((size_t)BSZ * CS * 4);          // 128 KB
    __bf16* Xs  = (__bf16*)alloc((size_t)MR * CS * 2);           // 2.4 MB
    int*    lut = (int*)   alloc((size_t)TRIP * 4);
    __bf16* H   = (__bf16*)alloc((size_t)MTRI * RD * 2);         // 23 MB
    // Pair (46 MB) aliases Xc (9.6 MB): Xc dead after k_g1, pack runs after.
    char*   pxc = alloc((size_t)MTRI * CS * 2);                  // 46 MB
    __bf16* Xc   = (__bf16*)pxc;
    __bf16* Pair = (__bf16*)pxc;

    hipLaunchKernelGGL(k_prep, dim3(MR + 520 + 64 + 32 + 1), dim3(256), 0, stream,
                       X, pos, Wv, W1, W2, Xc, Wvg, W1g, W2g, lut);
    hipLaunchKernelGGL(k_qproj, dim3(BSZ, CS/64), dim3(256), 0, stream, Q, Wq, bq, Qp);

    // G1: Xs = relu(Xc@Wv+bv)+Qp ; M=2304 K=2080 N=512
    hipLaunchKernelGGL((k_mm<1>), dim3(MR/64, CS/64), dim3(256), 0, stream,
                       Xc, KP, Wvg, CS, bv, Qp, (void*)Xs, CS, KP, (const int*)lut);
    // pack: Pair = xi*xj (overwrites Xc region)
    hipLaunchKernelGGL(k_pack, dim3(TRIP/8, BSZ), dim3(256), 0, stream,
                       Xs, (const int*)lut, Pair);
    // G2: H = relu(Pair@W1+b1) ; M=45056 K=512 N=256
    hipLaunchKernelGGL((k_mm<3>), dim3(MTRI/64, RD/64), dim3(256), 0, stream,
                       Pair, CS, W1g, RD, b1, nullptr, (void*)H, RD, CS, (const int*)lut);
    // G3: out = relu(H@W2+b2), dual-store ; M=45056 K=256 N=256
    hipLaunchKernelGGL((k_mm<2>), dim3(MTRI/64, RD/64), dim3(256), 0, stream,
                       H, RD, W2g, RD, b2, nullptr, d_out, RD, RD, (const int*)lut);
}

// Round 11
// 107.603 us; speedup vs baseline: 1.3671x; 1.3671x over previous
//
#include <hip/hip_runtime.h>
#include <hip/hip_bf16.h>
#include <stdint.h>

#define BSZ 64
#define NRG 36
#define VD  2048
#define QD  1024
#define CS  512
#define RD  256
#define KP  2080                 // 2052 padded to 32
#define MR  (BSZ*NRG)            // 2304
#define TRI  666                 // upper-triangle pairs (i<=j) per batch
#define TRIQ 768                 // padded per-batch rows: 12 chunks of 64

typedef __bf16 bf16x8 __attribute__((ext_vector_type(8)));
typedef float  f32x4  __attribute__((ext_vector_type(4)));

static __device__ __forceinline__ f32x4 mfma16(bf16x8 a, bf16x8 b, f32x4 c) {
    return __builtin_amdgcn_mfma_f32_16x16x32_bf16(a, b, c, 0, 0, 0);
}

// async global->LDS, 16B per lane (dest = wave-uniform base + lane*16)
static __device__ __forceinline__ void load_lds16(const __bf16* g, __bf16* l) {
    __builtin_amdgcn_global_load_lds(
        (const __attribute__((address_space(1))) uint32_t*)(const void*)g,
        (__attribute__((address_space(3))) uint32_t*)(void*)l,
        16, 0, 0);
}

// ---- merged prep: Xc rows, 3 g-major weights, tri LUT ----
__global__ __launch_bounds__(256) void k_prep(
    const float* __restrict__ X, const float* __restrict__ pos,
    const float* __restrict__ Wv, const float* __restrict__ W1,
    const float* __restrict__ W2,
    __bf16* __restrict__ Xc, __bf16* __restrict__ Wvg,
    __bf16* __restrict__ W1g, __bf16* __restrict__ W2g,
    int* __restrict__ lut)
{
    int id = blockIdx.x;
    if (id < MR) {               // ---- Xc row: [X | pos | 0-pad] ----
        const float* xr = X + (size_t)id * VD;
        const float* pr = pos + (size_t)id * 4;
        __bf16* o = Xc + (size_t)id * KP;
        for (int c = threadIdx.x; c < KP; c += 256) {
            float v = 0.f;
            if (c < VD) v = xr[c];
            else if (c < VD + 4) v = pr[c - VD];
            o[c] = (__bf16)v;
        }
        return;
    }
    id -= MR;
    if (id < 520 + 64 + 32) {    // ---- weight tile -> Wg[k/8][N][8] ----
        const float* W; __bf16* Wg; int K, N, nbx;
        if (id < 520)      {          W = Wv; Wg = Wvg; K = VD + 4; N = CS; nbx = CS / 64; }
        else if (id < 584) { id -= 520; W = W1; Wg = W1g; K = CS;     N = RD; nbx = RD / 64; }
        else               { id -= 584; W = W2; Wg = W2g; K = RD;     N = RD; nbx = RD / 64; }
        int bx = id % nbx, by = id / nbx;
        int g = by * 4 + (threadIdx.x >> 6);
        int n = bx * 64 + (threadIdx.x & 63);
        bf16x8 v;
        #pragma unroll
        for (int e = 0; e < 8; ++e) {
            int k = g * 8 + e;
            v[e] = (__bf16)((k < K) ? W[(size_t)k * N + n] : 0.f);
        }
        *(bf16x8*)(Wg + ((size_t)g * N + n) * 8) = v;
        return;
    }
    // ---- lut ----
    for (int t = threadIdx.x; t < TRIQ; t += 256) {
        int tt = (t < TRI) ? t : (TRI - 1);
        int i = 0;
        while (tt >= NRG - i) { tt -= NRG - i; ++i; }
        lut[t] = (i << 8) | (i + tt);
    }
}

// ---- Qp[b][c] = relu(Q[b]@Wq[:,c] + bq[c]) fp32, split-K parallel ----
__global__ __launch_bounds__(256) void k_qproj(
    const float* __restrict__ Q, const float* __restrict__ Wq,
    const float* __restrict__ bq, float* __restrict__ Qp) {
    int b   = blockIdx.x;
    int col = blockIdx.y * 64 + (threadIdx.x & 63);
    int ks  = threadIdx.x >> 6;
    const float* q = Q  + (size_t)b * QD + ks * 256;
    const float* w = Wq + (size_t)(ks * 256) * CS + col;
    float acc = 0.f;
    #pragma unroll 8
    for (int k = 0; k < 256; ++k)
        acc = fmaf(q[k], w[(size_t)k * CS], acc);
    __shared__ float red[256];
    red[threadIdx.x] = acc;
    __syncthreads();
    if (ks == 0) {
        float v = red[threadIdx.x] + red[threadIdx.x + 64]
                + red[threadIdx.x + 128] + red[threadIdx.x + 192] + bq[col];
        Qp[(size_t)b * CS + col] = fmaxf(v, 0.f);
    }
}

// ---- G1: Xs = relu(Xc @ Wv + bv) + Qp[b], ring-4 LDS, counted vmcnt ----
__global__ __launch_bounds__(256) void k_g1(
    const __bf16* __restrict__ Xc,   // [MR][KP]
    const __bf16* __restrict__ Wvg,  // [KP/8][CS][8]
    const float* __restrict__ bv,
    const float* __restrict__ Qp,    // [BSZ][CS]
    __bf16* __restrict__ Xs)         // [MR][CS]
{
    __shared__ __align__(16) __bf16 sA[4][4 * 64 * 8];
    __shared__ __align__(16) __bf16 sB[4][4 * 64 * 8];

    const int tid = threadIdx.x;
    const int lane = tid & 63;
    const int w = tid >> 6;
    const int wm = w & 1, wn = w >> 1;
    const int l15 = lane & 15, l4 = lane >> 4;
    const int m0 = blockIdx.x * 64;
    const int n0 = blockIdx.y * 64;
    const int sg = tid >> 6;
    const int sr = tid & 63;

    auto stage = [&](int kt, int slot) {
        load_lds16(Xc + (size_t)(m0 + sr) * KP + kt * 32 + sg * 8,
                   &sA[slot][0] + (size_t)tid * 8);
        load_lds16(Wvg + ((size_t)(kt * 4 + sg) * CS + n0 + sr) * 8,
                   &sB[slot][0] + (size_t)tid * 8);
    };

    constexpr int NKT = KP / 32;   // 65
    stage(0, 0);
    stage(1, 1);

    f32x4 acc[2][2] = {};
    for (int kt = 0; kt < NKT; ++kt) {
        if (kt + 2 < NKT) stage(kt + 2, (kt + 2) & 3);
        if (kt + 2 < NKT)      asm volatile("s_waitcnt vmcnt(4)" ::: "memory");
        else if (kt + 1 < NKT) asm volatile("s_waitcnt vmcnt(2)" ::: "memory");
        else                   asm volatile("s_waitcnt vmcnt(0)" ::: "memory");
        __builtin_amdgcn_s_barrier();

        const __bf16* a_base = &sA[kt & 3][0];
        const __bf16* b_base = &sB[kt & 3][0];
        bf16x8 af[2], bf[2];
        #pragma unroll
        for (int f = 0; f < 2; ++f)
            af[f] = *(const bf16x8*)(a_base + ((size_t)l4 * 64 + wm * 32 + f * 16 + l15) * 8);
        #pragma unroll
        for (int g = 0; g < 2; ++g)
            bf[g] = *(const bf16x8*)(b_base + ((size_t)l4 * 64 + wn * 32 + g * 16 + l15) * 8);
        __builtin_amdgcn_s_setprio(1);
        #pragma unroll
        for (int f = 0; f < 2; ++f)
            #pragma unroll
            for (int g = 0; g < 2; ++g)
                acc[f][g] = mfma16(af[f], bf[g], acc[f][g]);
        __builtin_amdgcn_s_setprio(0);
    }

    #pragma unroll
    for (int f = 0; f < 2; ++f) {
        int row0 = m0 + wm * 32 + f * 16 + l4 * 4;
        #pragma unroll
        for (int g = 0; g < 2; ++g) {
            int col = n0 + wn * 32 + g * 16 + l15;
            float bb = bv[col];
            #pragma unroll
            for (int r = 0; r < 4; ++r) {
                int row = row0 + r;
                float v = fmaxf(acc[f][g][r] + bb, 0.f) + Qp[(size_t)(row / NRG) * CS + col];
                Xs[(size_t)row * CS + col] = (__bf16)v;
            }
        }
    }
}

// ---- fused G2+G3 v6b: W in LDS ring-2 + interleave-robust counted vmcnt ----
__global__ __launch_bounds__(256, 3) void k_g23(
    const __bf16* __restrict__ Xs,   // [MR][CS]
    const __bf16* __restrict__ W1g,  // [CS/8][RD][8]
    const __bf16* __restrict__ W2g,  // [RD/8][RD][8]
    const float* __restrict__ b1,
    const float* __restrict__ b2,
    float* __restrict__ Out,         // [BSZ][NRG][NRG][RD]
    const int* __restrict__ lut)
{
    __shared__ __align__(16) __bf16 sW[2][4 * RD * 8];  // 2 x 16 KB ring
    __shared__ __align__(16) __bf16 sH[32 * RD];        // 16 KB [g2(32)][row(32)][8]

    const int tid = threadIdx.x;
    const int lane = tid & 63;
    const int w = tid >> 6;
    const int wm = w & 1, wn = w >> 1;   // stage1 wave = 32 rows x 128 cols
    const int l15 = lane & 15, l4 = lane >> 4;
    const int b = blockIdx.y;
    const int r_base = blockIdx.x * 64;

    const int t0 = r_base + wm * 32 + l15;
    const int ij0 = lut[t0], ij1 = lut[t0 + 16];
    const __bf16* xpi0 = Xs + (size_t)(b * NRG + (ij0 >> 8)) * CS + l4 * 8;
    const __bf16* xpj0 = Xs + (size_t)(b * NRG + (ij0 & 255)) * CS + l4 * 8;
    const __bf16* xpi1 = Xs + (size_t)(b * NRG + (ij1 >> 8)) * CS + l4 * 8;
    const __bf16* xpj1 = Xs + (size_t)(b * NRG + (ij1 & 255)) * CS + l4 * 8;

#define STG(WSRC, KT, SLOT) { \
    _Pragma("unroll") for (int it_ = 0; it_ < 4; ++it_) { \
        int c_ = tid + it_ * 256; \
        load_lds16((WSRC) + (size_t)(KT) * (RD * 32) + (size_t)c_ * 8, \
                   &sW[SLOT][0] + (size_t)c_ * 8); } }

    f32x4 acc0[8] = {}, acc1[8] = {};
    bf16x8 xiA0, xiA1, xjA0, xjA1, xiB0, xiB1, xjB0, xjB1;

    // prologue: W1 tile0 -> slot0, pair tile0 -> A set
    STG(W1g, 0, 0)
    xiA0 = *(const bf16x8*)xpi0; xiA1 = *(const bf16x8*)xpi1;
    xjA0 = *(const bf16x8*)xpj0; xjA1 = *(const bf16x8*)xpj1;

// per-iter: stage W(kt+1) + prefetch pair(kt+1), then wait for the ENTIRE
// older region {W(kt), pair(kt)} = 8 ops -> vmcnt(8) is interleave-robust
// (round-10 bug: vmcnt(12) assumed W-before-pair issue order).
#define S1_ITER(KT, XI0, XI1, XJ0, XJ1, XN0, XN1, XM0, XM1) { \
    if ((KT) < 15) { \
        STG(W1g, (KT) + 1, ((KT) + 1) & 1) \
        XN0 = *(const bf16x8*)(xpi0 + ((KT) + 1) * 32); \
        XN1 = *(const bf16x8*)(xpi1 + ((KT) + 1) * 32); \
        XM0 = *(const bf16x8*)(xpj0 + ((KT) + 1) * 32); \
        XM1 = *(const bf16x8*)(xpj1 + ((KT) + 1) * 32); \
        asm volatile("s_waitcnt vmcnt(8)" ::: "memory"); \
    } else { \
        asm volatile("s_waitcnt vmcnt(0)" ::: "memory"); \
    } \
    __builtin_amdgcn_s_barrier(); \
    bf16x8 af0_, af1_; \
    _Pragma("unroll") for (int e = 0; e < 8; ++e) { \
        af0_[e] = (__bf16)((float)XI0[e] * (float)XJ0[e]); \
        af1_[e] = (__bf16)((float)XI1[e] * (float)XJ1[e]); } \
    const __bf16* wb_ = &sW[(KT) & 1][0]; \
    __builtin_amdgcn_s_setprio(1); \
    _Pragma("unroll") for (int g = 0; g < 8; ++g) { \
        bf16x8 wf_ = *(const bf16x8*)(wb_ + ((size_t)l4 * RD + wn * 128 + g * 16 + l15) * 8); \
        acc0[g] = mfma16(af0_, wf_, acc0[g]); \
        acc1[g] = mfma16(af1_, wf_, acc1[g]); } \
    __builtin_amdgcn_s_setprio(0); \
    __builtin_amdgcn_s_barrier(); }

    S1_ITER(0,  xiA0, xiA1, xjA0, xjA1, xiB0, xiB1, xjB0, xjB1)
    S1_ITER(1,  xiB0, xiB1, xjB0, xjB1, xiA0, xiA1, xjA0, xjA1)
    S1_ITER(2,  xiA0, xiA1, xjA0, xjA1, xiB0, xiB1, xjB0, xjB1)
    S1_ITER(3,  xiB0, xiB1, xjB0, xjB1, xiA0, xiA1, xjA0, xjA1)
    S1_ITER(4,  xiA0, xiA1, xjA0, xjA1, xiB0, xiB1, xjB0, xjB1)
    S1_ITER(5,  xiB0, xiB1, xjB0, xjB1, xiA0, xiA1, xjA0, xjA1)
    S1_ITER(6,  xiA0, xiA1, xjA0, xjA1, xiB0, xiB1, xjB0, xjB1)
    S1_ITER(7,  xiB0, xiB1, xjB0, xjB1, xiA0, xiA1, xjA0, xjA1)
    S1_ITER(8,  xiA0, xiA1, xjA0, xjA1, xiB0, xiB1, xjB0, xjB1)
    S1_ITER(9,  xiB0, xiB1, xjB0, xjB1, xiA0, xiA1, xjA0, xjA1)
    S1_ITER(10, xiA0, xiA1, xjA0, xjA1, xiB0, xiB1, xjB0, xjB1)
    S1_ITER(11, xiB0, xiB1, xjB0, xjB1, xiA0, xiA1, xjA0, xjA1)
    S1_ITER(12, xiA0, xiA1, xjA0, xjA1, xiB0, xiB1, xjB0, xjB1)
    S1_ITER(13, xiB0, xiB1, xjB0, xjB1, xiA0, xiA1, xjA0, xjA1)
    S1_ITER(14, xiA0, xiA1, xjA0, xjA1, xiB0, xiB1, xjB0, xjB1)
    S1_ITER(15, xiB0, xiB1, xjB0, xjB1, xiA0, xiA1, xjA0, xjA1)

    // prefetch W2 tile0 into slot0 (slot0 last read at kt=14, barrier-protected)
    STG(W2g, 0, 0)

// transition: waves with wm==P write their 32 rows of H into sH
#define TRANS(P) { \
    if (wm == (P)) { \
        const int rw_ = l4 * 4; \
        _Pragma("unroll") for (int g = 0; g < 8; ++g) { \
            int col_ = wn * 128 + g * 16 + l15; \
            float bb_ = b1[col_]; \
            int g2_ = col_ >> 3, e_ = col_ & 7; \
            _Pragma("unroll") for (int r = 0; r < 4; ++r) { \
                sH[((size_t)g2_ * 32 + rw_ + r) * 8 + e_]      = (__bf16)fmaxf(acc0[g][r] + bb_, 0.f); \
                sH[((size_t)g2_ * 32 + 16 + rw_ + r) * 8 + e_] = (__bf16)fmaxf(acc1[g][r] + bb_, 0.f); } } } \
    asm volatile("s_waitcnt lgkmcnt(0)" ::: "memory"); \
    __builtin_amdgcn_s_barrier(); }

// stage2 iter: logical LT 0..15, tile LT&7, slot LT&1; wave = 32r x 64c (w*64)
// only the 4 STG ops live per region -> vmcnt(4) is exact and robust
#define S2_ITER(LT, ACC0, ACC1) { \
    if ((LT) < 15) { \
        STG(W2g, ((LT) + 1) & 7, ((LT) + 1) & 1) \
        asm volatile("s_waitcnt vmcnt(4)" ::: "memory"); \
    } else { \
        asm volatile("s_waitcnt vmcnt(0)" ::: "memory"); \
    } \
    __builtin_amdgcn_s_barrier(); \
    bf16x8 ah0_ = *(const bf16x8*)(sH + ((size_t)(((LT) & 7) * 4 + l4) * 32 + l15) * 8); \
    bf16x8 ah1_ = *(const bf16x8*)(sH + ((size_t)(((LT) & 7) * 4 + l4) * 32 + 16 + l15) * 8); \
    const __bf16* wb_ = &sW[(LT) & 1][0]; \
    __builtin_amdgcn_s_setprio(1); \
    _Pragma("unroll") for (int g = 0; g < 4; ++g) { \
        bf16x8 wf_ = *(const bf16x8*)(wb_ + ((size_t)l4 * RD + w * 64 + g * 16 + l15) * 8); \
        ACC0[g] = mfma16(ah0_, wf_, ACC0[g]); \
        ACC1[g] = mfma16(ah1_, wf_, ACC1[g]); } \
    __builtin_amdgcn_s_setprio(0); \
    __builtin_amdgcn_s_barrier(); }

// epilogue for pass P: rows r_base+P*32+{rw, 16+rw}, dual triangular store
#define EPI(P, ACC0, ACC1) { \
    float b2c_[4]; \
    _Pragma("unroll") for (int g = 0; g < 4; ++g) b2c_[g] = b2[w * 64 + g * 16 + l15]; \
    const int rw_ = l4 * 4; \
    _Pragma("unroll") for (int r = 0; r < 4; ++r) { \
        int ta_ = r_base + (P) * 32 + rw_ + r; \
        if (ta_ < TRI) { \
            int ij_ = lut[ta_]; int i_ = ij_ >> 8, j_ = ij_ & 255; \
            float* o1_ = Out + ((size_t)((b * NRG + i_) * NRG + j_)) * RD; \
            float* o2_ = Out + ((size_t)((b * NRG + j_) * NRG + i_)) * RD; \
            _Pragma("unroll") for (int g = 0; g < 4; ++g) { \
                int col_ = w * 64 + g * 16 + l15; \
                float v_ = fmaxf(ACC0[g][r] + b2c_[g], 0.f); \
                o1_[col_] = v_; o2_[col_] = v_; } } \
        int tb_ = r_base + (P) * 32 + 16 + rw_ + r; \
        if (tb_ < TRI) { \
            int ij_ = lut[tb_]; int i_ = ij_ >> 8, j_ = ij_ & 255; \
            float* o1_ = Out + ((size_t)((b * NRG + i_) * NRG + j_)) * RD; \
            float* o2_ = Out + ((size_t)((b * NRG + j_) * NRG + i_)) * RD; \
            _Pragma("unroll") for (int g = 0; g < 4; ++g) { \
                int col_ = w * 64 + g * 16 + l15; \
                float v_ = fmaxf(ACC1[g][r] + b2c_[g], 0.f); \
                o1_[col_] = v_; o2_[col_] = v_; } } } }

    // ---- pass 0 ----
    TRANS(0)
    {
        f32x4 a20[4] = {}, a21[4] = {};
        S2_ITER(0, a20, a21) S2_ITER(1, a20, a21) S2_ITER(2, a20, a21) S2_ITER(3, a20, a21)
        S2_ITER(4, a20, a21) S2_ITER(5, a20, a21) S2_ITER(6, a20, a21) S2_ITER(7, a20, a21)
        EPI(0, a20, a21)
    }
    __builtin_amdgcn_s_barrier();   // all waves done with sH pass 0
    // ---- pass 1 ----
    TRANS(1)
    {
        f32x4 a20[4] = {}, a21[4] = {};
        S2_ITER(8, a20, a21)  S2_ITER(9, a20, a21)  S2_ITER(10, a20, a21) S2_ITER(11, a20, a21)
        S2_ITER(12, a20, a21) S2_ITER(13, a20, a21) S2_ITER(14, a20, a21) S2_ITER(15, a20, a21)
        EPI(1, a20, a21)
    }
#undef STG
#undef S1_ITER
#undef TRANS
#undef S2_ITER
#undef EPI
}

extern "C" void kernel_launch(void* const* d_in, const int* in_sizes, int n_in,
                              void* d_out, int out_size, void* d_ws, size_t ws_size,
                              hipStream_t stream) {
    const float* X   = (const float*)d_in[0];
    const float* Q   = (const float*)d_in[1];
    const float* pos = (const float*)d_in[2];
    const float* Wv  = (const float*)d_in[3];
    const float* bv  = (const float*)d_in[4];
    const float* Wq  = (const float*)d_in[5];
    const float* bq  = (const float*)d_in[6];
    const float* W1  = (const float*)d_in[7];
    const float* b1  = (const float*)d_in[8];
    const float* W2  = (const float*)d_in[9];
    const float* b2  = (const float*)d_in[10];

    char* ws = (char*)d_ws;
    size_t off = 0;
    auto alloc = [&](size_t bytes) {
        char* p = ws + off;
        off = (off + bytes + 255) & ~(size_t)255;
        return p;
    };
    __bf16* Xc  = (__bf16*)alloc((size_t)MR * KP * 2);
    __bf16* Wvg = (__bf16*)alloc((size_t)(KP/8) * CS * 8 * 2);
    __bf16* W1g = (__bf16*)alloc((size_t)(CS/8) * RD * 8 * 2);
    __bf16* W2g = (__bf16*)alloc((size_t)(RD/8) * RD * 8 * 2);
    float*  Qp  = (float*) alloc((size_t)BSZ * CS * 4);
    __bf16* Xs  = (__bf16*)alloc((size_t)MR * CS * 2);
    int*    lut = (int*)   alloc((size_t)TRIQ * 4);

    hipLaunchKernelGGL(k_prep, dim3(MR + 520 + 64 + 32 + 1), dim3(256), 0, stream,
                       X, pos, Wv, W1, W2, Xc, Wvg, W1g, W2g, lut);
    hipLaunchKernelGGL(k_qproj, dim3(BSZ, CS/64), dim3(256), 0, stream, Q, Wq, bq, Qp);
    hipLaunchKernelGGL(k_g1,  dim3(MR/64, CS/64), dim3(256), 0, stream,
                       Xc, Wvg, bv, Qp, Xs);
    hipLaunchKernelGGL(k_g23, dim3(TRIQ/64, BSZ), dim3(256), 0, stream,
                       Xs, W1g, W2g, b1, b2, (float*)d_out, (const int*)lut);
}

// Round 12
// 106.725 us; speedup vs baseline: 1.3783x; 1.0082x over previous
//
#include <hip/hip_runtime.h>
#include <hip/hip_bf16.h>
#include <stdint.h>

#define BSZ 64
#define NRG 36
#define VD  2048
#define QD  1024
#define CS  512
#define RD  256
#define KP  2080                 // 2052 padded to 32
#define MR  (BSZ*NRG)            // 2304
#define TRI  666                 // upper-triangle pairs (i<=j) per batch
#define TRIQ 672                 // padded per-batch rows: 42 chunks of 16
#define CHB  42                  // 16-row chunks per batch
#define NCH  (BSZ*CHB)           // 2688 total 16-row chunks

typedef __bf16 bf16x8 __attribute__((ext_vector_type(8)));
typedef float  f32x4  __attribute__((ext_vector_type(4)));

static __device__ __forceinline__ f32x4 mfma16(bf16x8 a, bf16x8 b, f32x4 c) {
    return __builtin_amdgcn_mfma_f32_16x16x32_bf16(a, b, c, 0, 0, 0);
}

// async global->LDS, 16B per lane (dest = wave-uniform base + lane*16)
static __device__ __forceinline__ void load_lds16(const __bf16* g, __bf16* l) {
    __builtin_amdgcn_global_load_lds(
        (const __attribute__((address_space(1))) uint32_t*)(const void*)g,
        (__attribute__((address_space(3))) uint32_t*)(void*)l,
        16, 0, 0);
}

// ---- merged prep: Xc rows, 3 g-major weights, tri LUT, qproj ----
__global__ __launch_bounds__(256) void k_prep(
    const float* __restrict__ X, const float* __restrict__ pos,
    const float* __restrict__ Wv, const float* __restrict__ W1,
    const float* __restrict__ W2,
    const float* __restrict__ Q, const float* __restrict__ Wq,
    const float* __restrict__ bq,
    __bf16* __restrict__ Xc, __bf16* __restrict__ Wvg,
    __bf16* __restrict__ W1g, __bf16* __restrict__ W2g,
    int* __restrict__ lut, float* __restrict__ Qp)
{
    int id = blockIdx.x;
    if (id < MR) {               // ---- Xc row: [X | pos | 0-pad] ----
        const float* xr = X + (size_t)id * VD;
        const float* pr = pos + (size_t)id * 4;
        __bf16* o = Xc + (size_t)id * KP;
        for (int c = threadIdx.x; c < KP; c += 256) {
            float v = 0.f;
            if (c < VD) v = xr[c];
            else if (c < VD + 4) v = pr[c - VD];
            o[c] = (__bf16)v;
        }
        return;
    }
    id -= MR;
    if (id < 520 + 64 + 32) {    // ---- weight tile -> Wg[k/8][N][8] ----
        const float* W; __bf16* Wg; int K, N, nbx;
        if (id < 520)      {          W = Wv; Wg = Wvg; K = VD + 4; N = CS; nbx = CS / 64; }
        else if (id < 584) { id -= 520; W = W1; Wg = W1g; K = CS;     N = RD; nbx = RD / 64; }
        else               { id -= 584; W = W2; Wg = W2g; K = RD;     N = RD; nbx = RD / 64; }
        int bx = id % nbx, by = id / nbx;
        int g = by * 4 + (threadIdx.x >> 6);
        int n = bx * 64 + (threadIdx.x & 63);
        bf16x8 v;
        #pragma unroll
        for (int e = 0; e < 8; ++e) {
            int k = g * 8 + e;
            v[e] = (__bf16)((k < K) ? W[(size_t)k * N + n] : 0.f);
        }
        *(bf16x8*)(Wg + ((size_t)g * N + n) * 8) = v;
        return;
    }
    id -= 616;
    if (id == 0) {               // ---- lut ----
        for (int t = threadIdx.x; t < TRIQ; t += 256) {
            int tt = (t < TRI) ? t : (TRI - 1);
            int i = 0;
            while (tt >= NRG - i) { tt -= NRG - i; ++i; }
            lut[t] = (i << 8) | (i + tt);
        }
        return;
    }
    id -= 1;                     // ---- qproj: 512 blocks ----
    {
        int b   = id >> 3;
        int col = (id & 7) * 64 + (threadIdx.x & 63);
        int ks  = threadIdx.x >> 6;
        const float* q = Q  + (size_t)b * QD + ks * 256;
        const float* w = Wq + (size_t)(ks * 256) * CS + col;
        float acc = 0.f;
        #pragma unroll 8
        for (int k = 0; k < 256; ++k)
            acc = fmaf(q[k], w[(size_t)k * CS], acc);
        __shared__ float red[256];
        red[threadIdx.x] = acc;
        __syncthreads();
        if (ks == 0) {
            float v = red[threadIdx.x] + red[threadIdx.x + 64]
                    + red[threadIdx.x + 128] + red[threadIdx.x + 192] + bq[col];
            Qp[(size_t)b * CS + col] = fmaxf(v, 0.f);
        }
    }
}

// ---- G1: Xs = relu(Xc @ Wv + bv) + Qp[b], ring-4 LDS, counted vmcnt ----
__global__ __launch_bounds__(256) void k_g1(
    const __bf16* __restrict__ Xc,   // [MR][KP]
    const __bf16* __restrict__ Wvg,  // [KP/8][CS][8]
    const float* __restrict__ bv,
    const float* __restrict__ Qp,    // [BSZ][CS]
    __bf16* __restrict__ Xs)         // [MR][CS]
{
    __shared__ __align__(16) __bf16 sA[4][4 * 64 * 8];
    __shared__ __align__(16) __bf16 sB[4][4 * 64 * 8];

    const int tid = threadIdx.x;
    const int lane = tid & 63;
    const int w = tid >> 6;
    const int wm = w & 1, wn = w >> 1;
    const int l15 = lane & 15, l4 = lane >> 4;
    const int m0 = blockIdx.x * 64;
    const int n0 = blockIdx.y * 64;
    const int sg = tid >> 6;
    const int sr = tid & 63;

    auto stage = [&](int kt, int slot) {
        load_lds16(Xc + (size_t)(m0 + sr) * KP + kt * 32 + sg * 8,
                   &sA[slot][0] + (size_t)tid * 8);
        load_lds16(Wvg + ((size_t)(kt * 4 + sg) * CS + n0 + sr) * 8,
                   &sB[slot][0] + (size_t)tid * 8);
    };

    constexpr int NKT = KP / 32;   // 65
    stage(0, 0);
    stage(1, 1);

    f32x4 acc[2][2] = {};
    for (int kt = 0; kt < NKT; ++kt) {
        if (kt + 2 < NKT) stage(kt + 2, (kt + 2) & 3);
        if (kt + 2 < NKT)      asm volatile("s_waitcnt vmcnt(4)" ::: "memory");
        else if (kt + 1 < NKT) asm volatile("s_waitcnt vmcnt(2)" ::: "memory");
        else                   asm volatile("s_waitcnt vmcnt(0)" ::: "memory");
        __builtin_amdgcn_s_barrier();

        const __bf16* a_base = &sA[kt & 3][0];
        const __bf16* b_base = &sB[kt & 3][0];
        bf16x8 af[2], bf[2];
        #pragma unroll
        for (int f = 0; f < 2; ++f)
            af[f] = *(const bf16x8*)(a_base + ((size_t)l4 * 64 + wm * 32 + f * 16 + l15) * 8);
        #pragma unroll
        for (int g = 0; g < 2; ++g)
            bf[g] = *(const bf16x8*)(b_base + ((size_t)l4 * 64 + wn * 32 + g * 16 + l15) * 8);
        __builtin_amdgcn_s_setprio(1);
        #pragma unroll
        for (int f = 0; f < 2; ++f)
            #pragma unroll
            for (int g = 0; g < 2; ++g)
                acc[f][g] = mfma16(af[f], bf[g], acc[f][g]);
        __builtin_amdgcn_s_setprio(0);
    }

    #pragma unroll
    for (int f = 0; f < 2; ++f) {
        int row0 = m0 + wm * 32 + f * 16 + l4 * 4;
        #pragma unroll
        for (int g = 0; g < 2; ++g) {
            int col = n0 + wn * 32 + g * 16 + l15;
            float bb = bv[col];
            #pragma unroll
            for (int r = 0; r < 4; ++r) {
                int row = row0 + r;
                float v = fmaxf(acc[f][g][r] + bb, 0.f) + Qp[(size_t)(row / NRG) * CS + col];
                Xs[(size_t)row * CS + col] = (__bf16)v;
            }
        }
    }
}

// ---- G2: H = relu(pair @ W1 + b1), persistent-W, wave-independent ----
// 256 blocks x 768 thr (12 waves). Each wave owns one 16-row x 256-col task:
// 256 MFMA, no barriers inside. W1 staged in 4 K-quarter phases (64 KB LDS).
__global__ __launch_bounds__(768, 3) void k_g2(
    const __bf16* __restrict__ Xs,   // [MR][CS]
    const __bf16* __restrict__ W1g,  // [64][256][8] g-major
    const float* __restrict__ b1,
    const int* __restrict__ lut,
    __bf16* __restrict__ H)          // [NCH*16][RD]
{
    __shared__ __align__(16) __bf16 sW[4 * 4 * RD * 8];   // 64 KB: [pk4][g4][256][8]

    const int tid = threadIdx.x;
    const int lane = tid & 63;
    const int w = tid >> 6;
    const int l15 = lane & 15, l4 = lane >> 4;

    const int cw = w * 256 + blockIdx.x;          // striped task id
    const bool has = cw < NCH;
    const int c = has ? cw : 0;
    const int b = c / CHB;
    const int t0 = (c - b * CHB) * 16 + l15;
    const int ij = lut[t0];
    const __bf16* xpi = Xs + (size_t)(b * NRG + (ij >> 8)) * CS + l4 * 8;
    const __bf16* xpj = Xs + (size_t)(b * NRG + (ij & 255)) * CS + l4 * 8;

    f32x4 acc[16] = {};

    for (int phase = 0; phase < 4; ++phase) {
        // stage 64 KB quarter: 4096 16B-chunks over 768 threads
        #pragma unroll
        for (int it = 0; it < 6; ++it) {
            int q = it * 768 + tid;
            if (q < 4096)
                load_lds16(W1g + ((size_t)phase * 4096 + q) * 8, sW + (size_t)q * 8);
        }
        __syncthreads();
        if (has) {
            #pragma unroll
            for (int pk = 0; pk < 4; ++pk) {
                const int kt = phase * 4 + pk;
                bf16x8 xi = *(const bf16x8*)(xpi + kt * 32);
                bf16x8 xj = *(const bf16x8*)(xpj + kt * 32);
                bf16x8 af;
                #pragma unroll
                for (int e = 0; e < 8; ++e)
                    af[e] = (__bf16)((float)xi[e] * (float)xj[e]);
                const __bf16* wb = sW + (size_t)(pk * 4 + l4) * (RD * 8);
                #pragma unroll
                for (int g = 0; g < 16; ++g) {
                    bf16x8 wf = *(const bf16x8*)(wb + (size_t)(g * 16 + l15) * 8);
                    acc[g] = mfma16(af, wf, acc[g]);
                }
            }
        }
        __syncthreads();
    }

    if (has) {
        #pragma unroll
        for (int g = 0; g < 16; ++g) {
            int col = g * 16 + l15;
            float bb = b1[col];
            #pragma unroll
            for (int r = 0; r < 4; ++r) {
                int row = c * 16 + l4 * 4 + r;
                H[(size_t)row * RD + col] = (__bf16)fmaxf(acc[g][r] + bb, 0.f);
            }
        }
    }
}

// ---- G3: out = relu(H @ W2 + b2), persistent-W, dual triangular store ----
// 256 blocks x 768 thr. Each wave: one 16-row x 256-col task, 128 MFMA.
// W2 staged in 2 K-half phases (64 KB LDS).
__global__ __launch_bounds__(768, 3) void k_g3(
    const __bf16* __restrict__ H,    // [NCH*16][RD]
    const __bf16* __restrict__ W2g,  // [32][256][8] g-major
    const float* __restrict__ b2,
    const int* __restrict__ lut,
    float* __restrict__ Out)         // [BSZ][NRG][NRG][RD]
{
    __shared__ __align__(16) __bf16 sW[4 * 4 * RD * 8];   // 64 KB: [pk4][g4][256][8]

    const int tid = threadIdx.x;
    const int lane = tid & 63;
    const int w = tid >> 6;
    const int l15 = lane & 15, l4 = lane >> 4;

    const int cw = w * 256 + blockIdx.x;
    const bool has = cw < NCH;
    const int c = has ? cw : 0;
    const int b = c / CHB;
    const int tl = (c - b * CHB) * 16;           // base t within batch

    f32x4 acc[16] = {};

    for (int phase = 0; phase < 2; ++phase) {
        #pragma unroll
        for (int it = 0; it < 6; ++it) {
            int q = it * 768 + tid;
            if (q < 4096)
                load_lds16(W2g + ((size_t)phase * 4096 + q) * 8, sW + (size_t)q * 8);
        }
        __syncthreads();
        if (has) {
            #pragma unroll
            for (int pk = 0; pk < 4; ++pk) {
                const int kt = phase * 4 + pk;
                bf16x8 ah = *(const bf16x8*)(H + ((size_t)(c * 16 + l15)) * RD + kt * 32 + l4 * 8);
                const __bf16* wb = sW + (size_t)(pk * 4 + l4) * (RD * 8);
                #pragma unroll
                for (int g = 0; g < 16; ++g) {
                    bf16x8 wf = *(const bf16x8*)(wb + (size_t)(g * 16 + l15) * 8);
                    acc[g] = mfma16(ah, wf, acc[g]);
                }
            }
        }
        __syncthreads();
    }

    if (has) {
        float bc[16];
        #pragma unroll
        for (int g = 0; g < 16; ++g) bc[g] = b2[g * 16 + l15];
        #pragma unroll
        for (int r = 0; r < 4; ++r) {
            int t = tl + l4 * 4 + r;
            if (t < TRI) {
                int ij = lut[t];
                int i = ij >> 8, j = ij & 255;
                float* o1 = Out + ((size_t)((b * NRG + i) * NRG + j)) * RD;
                float* o2 = Out + ((size_t)((b * NRG + j) * NRG + i)) * RD;
                #pragma unroll
                for (int g = 0; g < 16; ++g) {
                    int col = g * 16 + l15;
                    float v = fmaxf(acc[g][r] + bc[g], 0.f);
                    o1[col] = v;
                    o2[col] = v;
                }
            }
        }
    }
}

extern "C" void kernel_launch(void* const* d_in, const int* in_sizes, int n_in,
                              void* d_out, int out_size, void* d_ws, size_t ws_size,
                              hipStream_t stream) {
    const float* X   = (const float*)d_in[0];
    const float* Q   = (const float*)d_in[1];
    const float* pos = (const float*)d_in[2];
    const float* Wv  = (const float*)d_in[3];
    const float* bv  = (const float*)d_in[4];
    const float* Wq  = (const float*)d_in[5];
    const float* bq  = (const float*)d_in[6];
    const float* W1  = (const float*)d_in[7];
    const float* b1  = (const float*)d_in[8];
    const float* W2  = (const float*)d_in[9];
    const float* b2  = (const float*)d_in[10];

    char* ws = (char*)d_ws;
    size_t off = 0;
    auto alloc = [&](size_t bytes) {
        char* p = ws + off;
        off = (off + bytes + 255) & ~(size_t)255;
        return p;
    };
    // H (22 MB) aliases Xc (9.6 MB): Xc dead after k_g1, H written by k_g2 after.
    size_t xcB = (size_t)MR * KP * 2;            // 9.6 MB
    size_t hB  = (size_t)NCH * 16 * RD * 2;      // 22 MB
    char*  rg0 = alloc(hB > xcB ? hB : xcB);
    __bf16* Xc  = (__bf16*)rg0;
    __bf16* H   = (__bf16*)rg0;
    __bf16* Wvg = (__bf16*)alloc((size_t)(KP/8) * CS * 8 * 2);
    __bf16* W1g = (__bf16*)alloc((size_t)(CS/8) * RD * 8 * 2);
    __bf16* W2g = (__bf16*)alloc((size_t)(RD/8) * RD * 8 * 2);
    float*  Qp  = (float*) alloc((size_t)BSZ * CS * 4);
    __bf16* Xs  = (__bf16*)alloc((size_t)MR * CS * 2);
    int*    lut = (int*)   alloc((size_t)TRIQ * 4);

    hipLaunchKernelGGL(k_prep, dim3(MR + 616 + 1 + 512), dim3(256), 0, stream,
                       X, pos, Wv, W1, W2, Q, Wq, bq,
                       Xc, Wvg, W1g, W2g, lut, Qp);
    hipLaunchKernelGGL(k_g1, dim3(MR/64, CS/64), dim3(256), 0, stream,
                       Xc, Wvg, bv, Qp, Xs);
    hipLaunchKernelGGL(k_g2, dim3(256), dim3(768), 0, stream,
                       Xs, W1g, b1, (const int*)lut, H);
    hipLaunchKernelGGL(k_g3, dim3(256), dim3(768), 0, stream,
                       H, W2g, b2, (const int*)lut, (float*)d_out);
}

// Round 13
// 100.439 us; speedup vs baseline: 1.4646x; 1.0626x over previous
//
#include <hip/hip_runtime.h>
#include <hip/hip_bf16.h>
#include <stdint.h>

#define BSZ 64
#define NRG 36
#define VD  2048
#define QD  1024
#define CS  512
#define RD  256
#define KP  2080                 // 2052 padded to 32
#define MR  (BSZ*NRG)            // 2304
#define TRI  666                 // upper-triangle pairs (i<=j) per batch
#define TRIQ 768                 // padded per-batch rows: 12 chunks of 64

typedef __bf16 bf16x8 __attribute__((ext_vector_type(8)));
typedef float  f32x4  __attribute__((ext_vector_type(4)));

static __device__ __forceinline__ f32x4 mfma16(bf16x8 a, bf16x8 b, f32x4 c) {
    return __builtin_amdgcn_mfma_f32_16x16x32_bf16(a, b, c, 0, 0, 0);
}

// async global->LDS, 16B per lane (dest = wave-uniform base + lane*16)
static __device__ __forceinline__ void load_lds16(const __bf16* g, __bf16* l) {
    __builtin_amdgcn_global_load_lds(
        (const __attribute__((address_space(1))) uint32_t*)(const void*)g,
        (__attribute__((address_space(3))) uint32_t*)(void*)l,
        16, 0, 0);
}

// ---- merged prep: Xc rows, 3 g-major weights, tri LUT, qproj ----
__global__ __launch_bounds__(256) void k_prep(
    const float* __restrict__ X, const float* __restrict__ pos,
    const float* __restrict__ Wv, const float* __restrict__ W1,
    const float* __restrict__ W2,
    const float* __restrict__ Q, const float* __restrict__ Wq,
    const float* __restrict__ bq,
    __bf16* __restrict__ Xc, __bf16* __restrict__ Wvg,
    __bf16* __restrict__ W1g, __bf16* __restrict__ W2g,
    int* __restrict__ lut, float* __restrict__ Qp)
{
    int id = blockIdx.x;
    if (id < MR) {               // ---- Xc row: [X | pos | 0-pad] ----
        const float* xr = X + (size_t)id * VD;
        const float* pr = pos + (size_t)id * 4;
        __bf16* o = Xc + (size_t)id * KP;
        for (int c = threadIdx.x; c < KP; c += 256) {
            float v = 0.f;
            if (c < VD) v = xr[c];
            else if (c < VD + 4) v = pr[c - VD];
            o[c] = (__bf16)v;
        }
        return;
    }
    id -= MR;
    if (id < 520 + 64 + 32) {    // ---- weight tile -> Wg[k/8][N][8] ----
        const float* W; __bf16* Wg; int K, N, nbx;
        if (id < 520)      {          W = Wv; Wg = Wvg; K = VD + 4; N = CS; nbx = CS / 64; }
        else if (id < 584) { id -= 520; W = W1; Wg = W1g; K = CS;     N = RD; nbx = RD / 64; }
        else               { id -= 584; W = W2; Wg = W2g; K = RD;     N = RD; nbx = RD / 64; }
        int bx = id % nbx, by = id / nbx;
        int g = by * 4 + (threadIdx.x >> 6);
        int n = bx * 64 + (threadIdx.x & 63);
        bf16x8 v;
        #pragma unroll
        for (int e = 0; e < 8; ++e) {
            int k = g * 8 + e;
            v[e] = (__bf16)((k < K) ? W[(size_t)k * N + n] : 0.f);
        }
        *(bf16x8*)(Wg + ((size_t)g * N + n) * 8) = v;
        return;
    }
    id -= 616;
    if (id == 0) {               // ---- lut ----
        for (int t = threadIdx.x; t < TRIQ; t += 256) {
            int tt = (t < TRI) ? t : (TRI - 1);
            int i = 0;
            while (tt >= NRG - i) { tt -= NRG - i; ++i; }
            lut[t] = (i << 8) | (i + tt);
        }
        return;
    }
    id -= 1;                     // ---- qproj: 512 blocks ----
    {
        int b   = id >> 3;
        int col = (id & 7) * 64 + (threadIdx.x & 63);
        int ks  = threadIdx.x >> 6;
        const float* q = Q  + (size_t)b * QD + ks * 256;
        const float* w = Wq + (size_t)(ks * 256) * CS + col;
        float acc = 0.f;
        #pragma unroll 8
        for (int k = 0; k < 256; ++k)
            acc = fmaf(q[k], w[(size_t)k * CS], acc);
        __shared__ float red[256];
        red[threadIdx.x] = acc;
        __syncthreads();
        if (ks == 0) {
            float v = red[threadIdx.x] + red[threadIdx.x + 64]
                    + red[threadIdx.x + 128] + red[threadIdx.x + 192] + bq[col];
            Qp[(size_t)b * CS + col] = fmaxf(v, 0.f);
        }
    }
}

// ---- G1: Xs = relu(Xc @ Wv + bv) + Qp[b], ring-4 LDS, counted vmcnt ----
__global__ __launch_bounds__(256) void k_g1(
    const __bf16* __restrict__ Xc,   // [MR][KP]
    const __bf16* __restrict__ Wvg,  // [KP/8][CS][8]
    const float* __restrict__ bv,
    const float* __restrict__ Qp,    // [BSZ][CS]
    __bf16* __restrict__ Xs)         // [MR][CS]
{
    __shared__ __align__(16) __bf16 sA[4][4 * 64 * 8];
    __shared__ __align__(16) __bf16 sB[4][4 * 64 * 8];

    const int tid = threadIdx.x;
    const int lane = tid & 63;
    const int w = tid >> 6;
    const int wm = w & 1, wn = w >> 1;
    const int l15 = lane & 15, l4 = lane >> 4;
    const int m0 = blockIdx.x * 64;
    const int n0 = blockIdx.y * 64;
    const int sg = tid >> 6;
    const int sr = tid & 63;

    auto stage = [&](int kt, int slot) {
        load_lds16(Xc + (size_t)(m0 + sr) * KP + kt * 32 + sg * 8,
                   &sA[slot][0] + (size_t)tid * 8);
        load_lds16(Wvg + ((size_t)(kt * 4 + sg) * CS + n0 + sr) * 8,
                   &sB[slot][0] + (size_t)tid * 8);
    };

    constexpr int NKT = KP / 32;   // 65
    stage(0, 0);
    stage(1, 1);

    f32x4 acc[2][2] = {};
    for (int kt = 0; kt < NKT; ++kt) {
        if (kt + 2 < NKT) stage(kt + 2, (kt + 2) & 3);
        if (kt + 2 < NKT)      asm volatile("s_waitcnt vmcnt(4)" ::: "memory");
        else if (kt + 1 < NKT) asm volatile("s_waitcnt vmcnt(2)" ::: "memory");
        else                   asm volatile("s_waitcnt vmcnt(0)" ::: "memory");
        __builtin_amdgcn_s_barrier();

        const __bf16* a_base = &sA[kt & 3][0];
        const __bf16* b_base = &sB[kt & 3][0];
        bf16x8 af[2], bf[2];
        #pragma unroll
        for (int f = 0; f < 2; ++f)
            af[f] = *(const bf16x8*)(a_base + ((size_t)l4 * 64 + wm * 32 + f * 16 + l15) * 8);
        #pragma unroll
        for (int g = 0; g < 2; ++g)
            bf[g] = *(const bf16x8*)(b_base + ((size_t)l4 * 64 + wn * 32 + g * 16 + l15) * 8);
        __builtin_amdgcn_s_setprio(1);
        #pragma unroll
        for (int f = 0; f < 2; ++f)
            #pragma unroll
            for (int g = 0; g < 2; ++g)
                acc[f][g] = mfma16(af[f], bf[g], acc[f][g]);
        __builtin_amdgcn_s_setprio(0);
    }

    #pragma unroll
    for (int f = 0; f < 2; ++f) {
        int row0 = m0 + wm * 32 + f * 16 + l4 * 4;
        #pragma unroll
        for (int g = 0; g < 2; ++g) {
            int col = n0 + wn * 32 + g * 16 + l15;
            float bb = bv[col];
            #pragma unroll
            for (int r = 0; r < 4; ++r) {
                int row = row0 + r;
                float v = fmaxf(acc[f][g][r] + bb, 0.f) + Qp[(size_t)(row / NRG) * CS + col];
                Xs[(size_t)row * CS + col] = (__bf16)v;
            }
        }
    }
}

// ---- fused G2+G3 v7: R4 structure + LDS-resident swizzled Xs[b]
//      (kills the TA-divergent pair loads). sH aliases sXs after stage 1.
//      LDS = 36 + 16 = 52 KB -> 3 blocks/CU. ----
__global__ __launch_bounds__(256, 3) void k_g23(
    const __bf16* __restrict__ Xs,   // [MR][CS]
    const __bf16* __restrict__ W1g,  // [CS/8][RD][8]
    const __bf16* __restrict__ W2g,  // [RD/8][RD][8]
    const float* __restrict__ b1,
    const float* __restrict__ b2,
    float* __restrict__ Out,         // [BSZ][NRG][NRG][RD]
    const int* __restrict__ lut)
{
    __shared__ __align__(16) __bf16 sXs[NRG * CS];   // 36 KB; becomes sH (32 KB)
    __shared__ __align__(16) __bf16 sB[4 * RD * 8];  // 16 KB W tile

    const int tid = threadIdx.x;
    const int lane = tid & 63;
    const int w = tid >> 6;
    const int wm = w & 1, wn = w >> 1;   // stage1 wave = 32 rows x 128 cols
    const int l15 = lane & 15, l4 = lane >> 4;
    const int b = blockIdx.y;
    const int r_base = blockIdx.x * 64;

    // ---- stage Xs[b] -> sXs, coalesced reads, chunk-swizzle cp^(r&7) ----
    {
        const __bf16* src = Xs + (size_t)b * NRG * CS;
        #pragma unroll
        for (int it = 0; it < 9; ++it) {
            int id = it * 256 + tid;          // 0..2303 chunks of 8 elems
            int r = id >> 6, cp = id & 63;    // wave-uniform r, lane-linear cp
            bf16x8 v = *(const bf16x8*)(src + (size_t)r * CS + cp * 8);
            int ba = (r << 10) | ((cp ^ (r & 7)) << 4);
            *(bf16x8*)((char*)sXs + ba) = v;
        }
    }

    const int t0 = r_base + wm * 32 + l15;
    const int ij0 = lut[t0], ij1 = lut[t0 + 16];
    const int i0 = ij0 >> 8, j0 = ij0 & 255;
    const int i1 = ij1 >> 8, j1 = ij1 & 255;

    __syncthreads();   // sXs ready

    // ---- stage 1: K=512, 16 k-tiles (R4 flow, pairs from LDS) ----
    f32x4 acc0[8] = {}, acc1[8] = {};
    for (int kt = 0; kt < 16; ++kt) {
        #pragma unroll
        for (int it = 0; it < 4; ++it) {
            int c = tid + it * 256;
            load_lds16(W1g + (size_t)kt * (RD * 32) + (size_t)c * 8, sB + (size_t)c * 8);
        }
        __syncthreads();

        const int kc = kt * 4 + l4;          // 16B-chunk index 0..63
        bf16x8 xi0 = *(const bf16x8*)((const char*)sXs + ((i0 << 10) | ((kc ^ (i0 & 7)) << 4)));
        bf16x8 xj0 = *(const bf16x8*)((const char*)sXs + ((j0 << 10) | ((kc ^ (j0 & 7)) << 4)));
        bf16x8 xi1 = *(const bf16x8*)((const char*)sXs + ((i1 << 10) | ((kc ^ (i1 & 7)) << 4)));
        bf16x8 xj1 = *(const bf16x8*)((const char*)sXs + ((j1 << 10) | ((kc ^ (j1 & 7)) << 4)));
        bf16x8 af0, af1;
        #pragma unroll
        for (int e = 0; e < 8; ++e) {
            af0[e] = (__bf16)((float)xi0[e] * (float)xj0[e]);
            af1[e] = (__bf16)((float)xi1[e] * (float)xj1[e]);
        }
        __builtin_amdgcn_s_setprio(1);
        #pragma unroll
        for (int g = 0; g < 8; ++g) {
            bf16x8 wf = *(const bf16x8*)(sB + ((size_t)l4 * RD + wn * 128 + g * 16 + l15) * 8);
            acc0[g] = mfma16(af0, wf, acc0[g]);
            acc1[g] = mfma16(af1, wf, acc1[g]);
        }
        __builtin_amdgcn_s_setprio(0);
        __syncthreads();
    }

    // ---- transition: H = relu(acc+b1) -> sH (aliases sXs) [g2][row64][8] ----
    __bf16* sH = sXs;
    #pragma unroll
    for (int g = 0; g < 8; ++g) {
        int col = wn * 128 + g * 16 + l15;
        float bb = b1[col];
        int g2 = col >> 3, e = col & 7;
        #pragma unroll
        for (int r = 0; r < 4; ++r) {
            int row0 = wm * 32 + l4 * 4;
            sH[((size_t)g2 * 64 + row0 + r) * 8 + e]      = (__bf16)fmaxf(acc0[g][r] + bb, 0.f);
            sH[((size_t)g2 * 64 + 16 + row0 + r) * 8 + e] = (__bf16)fmaxf(acc1[g][r] + bb, 0.f);
        }
    }
    __syncthreads();

    // ---- stage 2: K=256, 8 k-tiles (R4 flow verbatim) ----
    f32x4 acc20[8] = {}, acc21[8] = {};
    for (int kt = 0; kt < 8; ++kt) {
        #pragma unroll
        for (int it = 0; it < 4; ++it) {
            int c = tid + it * 256;
            load_lds16(W2g + (size_t)kt * (RD * 32) + (size_t)c * 8, sB + (size_t)c * 8);
        }
        __syncthreads();
        bf16x8 ah0 = *(const bf16x8*)(sH + ((size_t)(kt * 4 + l4) * 64 + wm * 32 + l15) * 8);
        bf16x8 ah1 = *(const bf16x8*)(sH + ((size_t)(kt * 4 + l4) * 64 + wm * 32 + 16 + l15) * 8);
        __builtin_amdgcn_s_setprio(1);
        #pragma unroll
        for (int g = 0; g < 8; ++g) {
            bf16x8 wf = *(const bf16x8*)(sB + ((size_t)l4 * RD + wn * 128 + g * 16 + l15) * 8);
            acc20[g] = mfma16(ah0, wf, acc20[g]);
            acc21[g] = mfma16(ah1, wf, acc21[g]);
        }
        __builtin_amdgcn_s_setprio(0);
        __syncthreads();
    }

    // ---- epilogue: dual-store fp32 (R4 verbatim) ----
    float bias2[8];
    #pragma unroll
    for (int g = 0; g < 8; ++g) bias2[g] = b2[wn * 128 + g * 16 + l15];
    const int rw = wm * 32 + l4 * 4;
    #pragma unroll
    for (int r = 0; r < 4; ++r) {
        int ta = r_base + rw + r;
        if (ta < TRI) {
            int ij = lut[ta];
            int i = ij >> 8, j = ij & 255;
            float* o1 = Out + ((size_t)((b * NRG + i) * NRG + j)) * RD;
            float* o2 = Out + ((size_t)((b * NRG + j) * NRG + i)) * RD;
            #pragma unroll
            for (int g = 0; g < 8; ++g) {
                int col = wn * 128 + g * 16 + l15;
                float v = fmaxf(acc20[g][r] + bias2[g], 0.f);
                o1[col] = v; o2[col] = v;
            }
        }
        int tb = r_base + rw + 16 + r;
        if (tb < TRI) {
            int ij = lut[tb];
            int i = ij >> 8, j = ij & 255;
            float* o1 = Out + ((size_t)((b * NRG + i) * NRG + j)) * RD;
            float* o2 = Out + ((size_t)((b * NRG + j) * NRG + i)) * RD;
            #pragma unroll
            for (int g = 0; g < 8; ++g) {
                int col = wn * 128 + g * 16 + l15;
                float v = fmaxf(acc21[g][r] + bias2[g], 0.f);
                o1[col] = v; o2[col] = v;
            }
        }
    }
}

extern "C" void kernel_launch(void* const* d_in, const int* in_sizes, int n_in,
                              void* d_out, int out_size, void* d_ws, size_t ws_size,
                              hipStream_t stream) {
    const float* X   = (const float*)d_in[0];
    const float* Q   = (const float*)d_in[1];
    const float* pos = (const float*)d_in[2];
    const float* Wv  = (const float*)d_in[3];
    const float* bv  = (const float*)d_in[4];
    const float* Wq  = (const float*)d_in[5];
    const float* bq  = (const float*)d_in[6];
    const float* W1  = (const float*)d_in[7];
    const float* b1  = (const float*)d_in[8];
    const float* W2  = (const float*)d_in[9];
    const float* b2  = (const float*)d_in[10];

    char* ws = (char*)d_ws;
    size_t off = 0;
    auto alloc = [&](size_t bytes) {
        char* p = ws + off;
        off = (off + bytes + 255) & ~(size_t)255;
        return p;
    };
    __bf16* Xc  = (__bf16*)alloc((size_t)MR * KP * 2);
    __bf16* Wvg = (__bf16*)alloc((size_t)(KP/8) * CS * 8 * 2);
    __bf16* W1g = (__bf16*)alloc((size_t)(CS/8) * RD * 8 * 2);
    __bf16* W2g = (__bf16*)alloc((size_t)(RD/8) * RD * 8 * 2);
    float*  Qp  = (float*) alloc((size_t)BSZ * CS * 4);
    __bf16* Xs  = (__bf16*)alloc((size_t)MR * CS * 2);
    int*    lut = (int*)   alloc((size_t)TRIQ * 4);

    hipLaunchKernelGGL(k_prep, dim3(MR + 616 + 1 + 512), dim3(256), 0, stream,
                       X, pos, Wv, W1, W2, Q, Wq, bq,
                       Xc, Wvg, W1g, W2g, lut, Qp);
    hipLaunchKernelGGL(k_g1, dim3(MR/64, CS/64), dim3(256), 0, stream,
                       Xc, Wvg, bv, Qp, Xs);
    hipLaunchKernelGGL(k_g23, dim3(TRIQ/64, BSZ), dim3(256), 0, stream,
                       Xs, W1g, W2g, b1, b2, (float*)d_out, (const int*)lut);
}

// Round 14
// 98.821 us; speedup vs baseline: 1.4885x; 1.0164x over previous
//
#include <hip/hip_runtime.h>
#include <hip/hip_bf16.h>
#include <stdint.h>

#define BSZ 64
#define NRG 36
#define VD  2048
#define QD  1024
#define CS  512
#define RD  256
#define KP  2080                 // 2052 padded to 32
#define MR  (BSZ*NRG)            // 2304
#define TRI  666                 // upper-triangle pairs (i<=j) per batch
#define TRIQ 768                 // padded per-batch rows: 4 chunks of 192

typedef __bf16 bf16x8 __attribute__((ext_vector_type(8)));
typedef float  f32x4  __attribute__((ext_vector_type(4)));

static __device__ __forceinline__ f32x4 mfma16(bf16x8 a, bf16x8 b, f32x4 c) {
    return __builtin_amdgcn_mfma_f32_16x16x32_bf16(a, b, c, 0, 0, 0);
}

// async global->LDS, 16B per lane (dest = wave-uniform base + lane*16)
static __device__ __forceinline__ void load_lds16(const __bf16* g, __bf16* l) {
    __builtin_amdgcn_global_load_lds(
        (const __attribute__((address_space(1))) uint32_t*)(const void*)g,
        (__attribute__((address_space(3))) uint32_t*)(void*)l,
        16, 0, 0);
}

// ---- merged prep: Xc rows, 3 g-major weights, tri LUT, qproj ----
__global__ __launch_bounds__(256) void k_prep(
    const float* __restrict__ X, const float* __restrict__ pos,
    const float* __restrict__ Wv, const float* __restrict__ W1,
    const float* __restrict__ W2,
    const float* __restrict__ Q, const float* __restrict__ Wq,
    const float* __restrict__ bq,
    __bf16* __restrict__ Xc, __bf16* __restrict__ Wvg,
    __bf16* __restrict__ W1g, __bf16* __restrict__ W2g,
    int* __restrict__ lut, float* __restrict__ Qp)
{
    int id = blockIdx.x;
    if (id < MR) {               // ---- Xc row: [X | pos | 0-pad] ----
        const float* xr = X + (size_t)id * VD;
        const float* pr = pos + (size_t)id * 4;
        __bf16* o = Xc + (size_t)id * KP;
        for (int c = threadIdx.x; c < KP; c += 256) {
            float v = 0.f;
            if (c < VD) v = xr[c];
            else if (c < VD + 4) v = pr[c - VD];
            o[c] = (__bf16)v;
        }
        return;
    }
    id -= MR;
    if (id < 520 + 64 + 32) {    // ---- weight tile -> Wg[k/8][N][8] ----
        const float* W; __bf16* Wg; int K, N, nbx;
        if (id < 520)      {          W = Wv; Wg = Wvg; K = VD + 4; N = CS; nbx = CS / 64; }
        else if (id < 584) { id -= 520; W = W1; Wg = W1g; K = CS;     N = RD; nbx = RD / 64; }
        else               { id -= 584; W = W2; Wg = W2g; K = RD;     N = RD; nbx = RD / 64; }
        int bx = id % nbx, by = id / nbx;
        int g = by * 4 + (threadIdx.x >> 6);
        int n = bx * 64 + (threadIdx.x & 63);
        bf16x8 v;
        #pragma unroll
        for (int e = 0; e < 8; ++e) {
            int k = g * 8 + e;
            v[e] = (__bf16)((k < K) ? W[(size_t)k * N + n] : 0.f);
        }
        *(bf16x8*)(Wg + ((size_t)g * N + n) * 8) = v;
        return;
    }
    id -= 616;
    if (id == 0) {               // ---- lut ----
        for (int t = threadIdx.x; t < TRIQ; t += 256) {
            int tt = (t < TRI) ? t : (TRI - 1);
            int i = 0;
            while (tt >= NRG - i) { tt -= NRG - i; ++i; }
            lut[t] = (i << 8) | (i + tt);
        }
        return;
    }
    id -= 1;                     // ---- qproj: 512 blocks ----
    {
        int b   = id >> 3;
        int col = (id & 7) * 64 + (threadIdx.x & 63);
        int ks  = threadIdx.x >> 6;
        const float* q = Q  + (size_t)b * QD + ks * 256;
        const float* w = Wq + (size_t)(ks * 256) * CS + col;
        float acc = 0.f;
        #pragma unroll 8
        for (int k = 0; k < 256; ++k)
            acc = fmaf(q[k], w[(size_t)k * CS], acc);
        __shared__ float red[256];
        red[threadIdx.x] = acc;
        __syncthreads();
        if (ks == 0) {
            float v = red[threadIdx.x] + red[threadIdx.x + 64]
                    + red[threadIdx.x + 128] + red[threadIdx.x + 192] + bq[col];
            Qp[(size_t)b * CS + col] = fmaxf(v, 0.f);
        }
    }
}

// ---- G1: Xs = relu(Xc @ Wv + bv) + Qp[b], ring-4 LDS, counted vmcnt ----
__global__ __launch_bounds__(256) void k_g1(
    const __bf16* __restrict__ Xc,   // [MR][KP]
    const __bf16* __restrict__ Wvg,  // [KP/8][CS][8]
    const float* __restrict__ bv,
    const float* __restrict__ Qp,    // [BSZ][CS]
    __bf16* __restrict__ Xs)         // [MR][CS]
{
    __shared__ __align__(16) __bf16 sA[4][4 * 64 * 8];
    __shared__ __align__(16) __bf16 sB[4][4 * 64 * 8];

    const int tid = threadIdx.x;
    const int lane = tid & 63;
    const int w = tid >> 6;
    const int wm = w & 1, wn = w >> 1;
    const int l15 = lane & 15, l4 = lane >> 4;
    const int m0 = blockIdx.x * 64;
    const int n0 = blockIdx.y * 64;
    const int sg = tid >> 6;
    const int sr = tid & 63;

    auto stage = [&](int kt, int slot) {
        load_lds16(Xc + (size_t)(m0 + sr) * KP + kt * 32 + sg * 8,
                   &sA[slot][0] + (size_t)tid * 8);
        load_lds16(Wvg + ((size_t)(kt * 4 + sg) * CS + n0 + sr) * 8,
                   &sB[slot][0] + (size_t)tid * 8);
    };

    constexpr int NKT = KP / 32;   // 65
    stage(0, 0);
    stage(1, 1);

    f32x4 acc[2][2] = {};
    for (int kt = 0; kt < NKT; ++kt) {
        if (kt + 2 < NKT) stage(kt + 2, (kt + 2) & 3);
        if (kt + 2 < NKT)      asm volatile("s_waitcnt vmcnt(4)" ::: "memory");
        else if (kt + 1 < NKT) asm volatile("s_waitcnt vmcnt(2)" ::: "memory");
        else                   asm volatile("s_waitcnt vmcnt(0)" ::: "memory");
        __builtin_amdgcn_s_barrier();

        const __bf16* a_base = &sA[kt & 3][0];
        const __bf16* b_base = &sB[kt & 3][0];
        bf16x8 af[2], bf[2];
        #pragma unroll
        for (int f = 0; f < 2; ++f)
            af[f] = *(const bf16x8*)(a_base + ((size_t)l4 * 64 + wm * 32 + f * 16 + l15) * 8);
        #pragma unroll
        for (int g = 0; g < 2; ++g)
            bf[g] = *(const bf16x8*)(b_base + ((size_t)l4 * 64 + wn * 32 + g * 16 + l15) * 8);
        __builtin_amdgcn_s_setprio(1);
        #pragma unroll
        for (int f = 0; f < 2; ++f)
            #pragma unroll
            for (int g = 0; g < 2; ++g)
                acc[f][g] = mfma16(af[f], bf[g], acc[f][g]);
        __builtin_amdgcn_s_setprio(0);
    }

    #pragma unroll
    for (int f = 0; f < 2; ++f) {
        int row0 = m0 + wm * 32 + f * 16 + l4 * 4;
        #pragma unroll
        for (int g = 0; g < 2; ++g) {
            int col = n0 + wn * 32 + g * 16 + l15;
            float bb = bv[col];
            #pragma unroll
            for (int r = 0; r < 4; ++r) {
                int row = row0 + r;
                float v = fmaxf(acc[f][g][r] + bb, 0.f) + Qp[(size_t)(row / NRG) * CS + col];
                Xs[(size_t)row * CS + col] = (__bf16)v;
            }
        }
    }
}

// ---- fused G2+G3 v8: 1 block/CU (12 waves, 128 KB LDS), M=192/block.
//      W staged once per CU per tile (3x less L2), sXs unioned in sH,
//      ring-2 sW with raw barriers; only W loads in VMEM queue. ----
__global__ __launch_bounds__(768, 1) void k_g23(
    const __bf16* __restrict__ Xs,   // [MR][CS]
    const __bf16* __restrict__ W1g,  // [CS/8][RD][8]
    const __bf16* __restrict__ W2g,  // [RD/8][RD][8]
    const float* __restrict__ b1,
    const float* __restrict__ b2,
    float* __restrict__ Out,         // [BSZ][NRG][NRG][RD]
    const int* __restrict__ lut)
{
    // union: first 36 KB = sXs (stage 1), whole 96 KB = sH (stage 2)
    __shared__ __align__(16) __bf16 uni[32 * 192 * 8];     // 96 KB
    __shared__ __align__(16) __bf16 sW[2][4 * RD * 8];     // 2 x 16 KB

    const int tid = threadIdx.x;
    const int lane = tid & 63;
    const int w = tid >> 6;          // 12 waves
    const int mg = w >> 1;           // 0..5 : 32-row group
    const int nh = w & 1;            // 0..1 : 128-col half
    const int l15 = lane & 15, l4 = lane >> 4;
    const int b = blockIdx.y;
    const int r_base = blockIdx.x * 192;
    const char* sXc = (const char*)uni;

    // ---- stage Xs[b] -> sXs (coalesced, chunk-swizzle cp^(r&7)) ----
    {
        const __bf16* src = Xs + (size_t)b * NRG * CS;
        #pragma unroll
        for (int it = 0; it < 3; ++it) {
            int id = it * 768 + tid;          // 0..2303 chunks of 8 elems
            int r = id >> 6, cp = id & 63;
            bf16x8 v = *(const bf16x8*)(src + (size_t)r * CS + cp * 8);
            int ba = (r << 10) | ((cp ^ (r & 7)) << 4);
            *(bf16x8*)((char*)uni + ba) = v;
        }
    }
    const int t0 = r_base + mg * 32 + l15;
    const int ij0 = lut[t0], ij1 = lut[t0 + 16];
    const int i0 = ij0 >> 8, j0 = ij0 & 255;
    const int i1 = ij1 >> 8, j1 = ij1 & 255;

    asm volatile("s_waitcnt lgkmcnt(0)" ::: "memory");
    __builtin_amdgcn_s_barrier();     // sXs ready

    const bool stager = (tid < 256);
    // stage one 16KB W tile: 1024 chunks over 256 stager threads
#define STG(SRC, KT, SLOT) { \
    _Pragma("unroll") for (int it_ = 0; it_ < 4; ++it_) { \
        int c_ = tid + it_ * 256; \
        load_lds16((SRC) + (size_t)(KT) * (RD * 32) + (size_t)c_ * 8, \
                   &sW[SLOT][0] + (size_t)c_ * 8); } }

    if (stager) STG(W1g, 0, 0)

    // ---- stage 1: K=512, 16 tiles; one barrier per tile ----
    f32x4 acc[2][8] = {};
    for (int kt = 0; kt < 16; ++kt) {
        if (stager) asm volatile("s_waitcnt vmcnt(0)" ::: "memory");
        __builtin_amdgcn_s_barrier();          // tile kt in LDS, prev slot free
        if (stager) {
            if (kt < 15) { STG(W1g, kt + 1, (kt + 1) & 1) }
            else         { STG(W2g, 0, 0) }     // W2 tile0 -> slot 0
        }
        const int kc = kt * 4 + l4;
        bf16x8 xi0 = *(const bf16x8*)(sXc + ((i0 << 10) | ((kc ^ (i0 & 7)) << 4)));
        bf16x8 xj0 = *(const bf16x8*)(sXc + ((j0 << 10) | ((kc ^ (j0 & 7)) << 4)));
        bf16x8 xi1 = *(const bf16x8*)(sXc + ((i1 << 10) | ((kc ^ (i1 & 7)) << 4)));
        bf16x8 xj1 = *(const bf16x8*)(sXc + ((j1 << 10) | ((kc ^ (j1 & 7)) << 4)));
        bf16x8 af0, af1;
        #pragma unroll
        for (int e = 0; e < 8; ++e) {
            af0[e] = (__bf16)((float)xi0[e] * (float)xj0[e]);
            af1[e] = (__bf16)((float)xi1[e] * (float)xj1[e]);
        }
        const __bf16* wb = &sW[kt & 1][0];
        __builtin_amdgcn_s_setprio(1);
        #pragma unroll
        for (int g = 0; g < 8; ++g) {
            bf16x8 wf = *(const bf16x8*)(wb + ((size_t)l4 * RD + nh * 128 + g * 16 + l15) * 8);
            acc[0][g] = mfma16(af0, wf, acc[0][g]);
            acc[1][g] = mfma16(af1, wf, acc[1][g]);
        }
        __builtin_amdgcn_s_setprio(0);
    }

    __builtin_amdgcn_s_barrier();   // all done reading sXs (about to clobber)

    // ---- transition: H = relu(acc+b1) -> sH[kc2(32)][row(192)][8] ----
    #pragma unroll
    for (int g = 0; g < 8; ++g) {
        int col = nh * 128 + g * 16 + l15;
        float bb = b1[col];
        int kc2 = col >> 3, e = col & 7;
        #pragma unroll
        for (int fm = 0; fm < 2; ++fm) {
            int row0 = mg * 32 + fm * 16 + l4 * 4;
            #pragma unroll
            for (int r = 0; r < 4; ++r) {
                float v = fmaxf(acc[fm][g][r] + bb, 0.f);
                uni[((size_t)kc2 * 192 + row0 + r) * 8 + e] = (__bf16)v;
            }
        }
    }
    asm volatile("s_waitcnt lgkmcnt(0)" ::: "memory");
    __builtin_amdgcn_s_barrier();   // sH published (W2 t0 still in flight)

    // ---- stage 2: K=256, 8 tiles (global T16..T23), wave = 32r x 128c ----
    f32x4 acc2[2][8] = {};
    for (int kt = 0; kt < 8; ++kt) {
        if (stager) asm volatile("s_waitcnt vmcnt(0)" ::: "memory");
        __builtin_amdgcn_s_barrier();
        if (stager && kt < 7) STG(W2g, kt + 1, (kt + 1) & 1)
        bf16x8 ah0, ah1;
        {
            int row0 = mg * 32 + l15;
            ah0 = *(const bf16x8*)(uni + ((size_t)(kt * 4 + l4) * 192 + row0) * 8);
            ah1 = *(const bf16x8*)(uni + ((size_t)(kt * 4 + l4) * 192 + row0 + 16) * 8);
        }
        const __bf16* wb = &sW[kt & 1][0];
        __builtin_amdgcn_s_setprio(1);
        #pragma unroll
        for (int g = 0; g < 8; ++g) {
            bf16x8 wf = *(const bf16x8*)(wb + ((size_t)l4 * RD + nh * 128 + g * 16 + l15) * 8);
            acc2[0][g] = mfma16(ah0, wf, acc2[0][g]);
            acc2[1][g] = mfma16(ah1, wf, acc2[1][g]);
        }
        __builtin_amdgcn_s_setprio(0);
    }

    // ---- epilogue: dual-store fp32 ----
    float bias2[8];
    #pragma unroll
    for (int g = 0; g < 8; ++g) bias2[g] = b2[nh * 128 + g * 16 + l15];
    #pragma unroll
    for (int fm = 0; fm < 2; ++fm) {
        int rw = mg * 32 + fm * 16 + l4 * 4;
        #pragma unroll
        for (int r = 0; r < 4; ++r) {
            int t = r_base + rw + r;
            if (t < TRI) {
                int ij = lut[t];
                int i = ij >> 8, j = ij & 255;
                float* o1 = Out + ((size_t)((b * NRG + i) * NRG + j)) * RD;
                float* o2 = Out + ((size_t)((b * NRG + j) * NRG + i)) * RD;
                #pragma unroll
                for (int g = 0; g < 8; ++g) {
                    int col = nh * 128 + g * 16 + l15;
                    float v = fmaxf(acc2[fm][g][r] + bias2[g], 0.f);
                    o1[col] = v; o2[col] = v;
                }
            }
        }
    }
#undef STG
}

extern "C" void kernel_launch(void* const* d_in, const int* in_sizes, int n_in,
                              void* d_out, int out_size, void* d_ws, size_t ws_size,
                              hipStream_t stream) {
    const float* X   = (const float*)d_in[0];
    const float* Q   = (const float*)d_in[1];
    const float* pos = (const float*)d_in[2];
    const float* Wv  = (const float*)d_in[3];
    const float* bv  = (const float*)d_in[4];
    const float* Wq  = (const float*)d_in[5];
    const float* bq  = (const float*)d_in[6];
    const float* W1  = (const float*)d_in[7];
    const float* b1  = (const float*)d_in[8];
    const float* W2  = (const float*)d_in[9];
    const float* b2  = (const float*)d_in[10];

    char* ws = (char*)d_ws;
    size_t off = 0;
    auto alloc = [&](size_t bytes) {
        char* p = ws + off;
        off = (off + bytes + 255) & ~(size_t)255;
        return p;
    };
    __bf16* Xc  = (__bf16*)alloc((size_t)MR * KP * 2);
    __bf16* Wvg = (__bf16*)alloc((size_t)(KP/8) * CS * 8 * 2);
    __bf16* W1g = (__bf16*)alloc((size_t)(CS/8) * RD * 8 * 2);
    __bf16* W2g = (__bf16*)alloc((size_t)(RD/8) * RD * 8 * 2);
    float*  Qp  = (float*) alloc((size_t)BSZ * CS * 4);
    __bf16* Xs  = (__bf16*)alloc((size_t)MR * CS * 2);
    int*    lut = (int*)   alloc((size_t)TRIQ * 4);

    hipLaunchKernelGGL(k_prep, dim3(MR + 616 + 1 + 512), dim3(256), 0, stream,
                       X, pos, Wv, W1, W2, Q, Wq, bq,
                       Xc, Wvg, W1g, W2g, lut, Qp);
    hipLaunchKernelGGL(k_g1, dim3(MR/64, CS/64), dim3(256), 0, stream,
                       Xc, Wvg, bv, Qp, Xs);
    hipLaunchKernelGGL(k_g23, dim3(4, BSZ), dim3(768), 0, stream,
                       Xs, W1g, W2g, b1, b2, (float*)d_out, (const int*)lut);
}